// Round 9
// baseline (159.562 us; speedup 1.0000x reference)
//
#include <hip/hip_runtime.h>
#include <hip/hip_bf16.h>

#define DI __device__ __forceinline__

using bf16x8 = __attribute__((ext_vector_type(8))) short;
using f32x4  = __attribute__((ext_vector_type(4))) float;
using f32x16 = __attribute__((ext_vector_type(16))) float;
using u16    = unsigned short;
using u16x4  = __attribute__((ext_vector_type(4))) unsigned short;

constexpr int Bc = 2, Sc = 2048, Hc = 768, NHc = 12, HDc = 64;
constexpr int Mc = Bc * Sc;                 // 4096 rows
constexpr float L2E = 1.4426950408889634f;

DI u16 f2bf(float f) {
  union { float f; unsigned u; } c; c.f = f;
  unsigned u = c.u;
  return (u16)((u + 0x7fffu + ((u >> 16) & 1u)) >> 16);   // RNE
}

DI unsigned f2bf2(float a, float b) {
  float2 t; t.x = a; t.y = b;
  __hip_bfloat162 h = __float22bfloat162_rn(t);
  union { __hip_bfloat162 h; unsigned u; } c; c.h = h;
  return c.u;
}

DI void gload_lds16(const void* g, void* l) {
  __builtin_amdgcn_global_load_lds(
      (__attribute__((address_space(1))) void*)(g),
      (__attribute__((address_space(3))) void*)(l), 16, 0, 0);
}

// ---------------- prep kernels ----------------

// also converts mask -> maskones bf16, PERMUTED within 16-groups (swap kv
// bits 2<->3) so attn's PV B-frag slots are one contiguous 16B chunk.
__global__ void cvt_bf16(const float* __restrict__ x, u16* __restrict__ y, int n4,
                         const int* __restrict__ maskg, u16* __restrict__ mones) {
  int i = blockIdx.x * 256 + threadIdx.x;
  if (i >= n4) return;
  float4 v = reinterpret_cast<const float4*>(x)[i];
  u16x4 o;
  o[0] = f2bf(v.x); o[1] = f2bf(v.y); o[2] = f2bf(v.z); o[3] = f2bf(v.w);
  reinterpret_cast<u16x4*>(y)[i] = o;
  if (i < Bc * Sc / 4) {
    int j = i & 3;
    int js = ((j & 1) << 1) | ((j >> 1) & 1);      // swap bits within quad
    int isrc = (i & ~3) | js;
    int4 mv = reinterpret_cast<const int4*>(maskg)[isrc];
    u16x4 m;
    m[0] = f2bf((float)mv.x); m[1] = f2bf((float)mv.y);
    m[2] = f2bf((float)mv.z); m[3] = f2bf((float)mv.w);
    reinterpret_cast<u16x4*>(mones)[i] = m;
  }
}

// Wt[n][k] = W[k][n], bf16
__global__ void wtrans(const float* __restrict__ Wq, const float* __restrict__ Wk,
                       const float* __restrict__ Wv, const float* __restrict__ Wo,
                       u16* __restrict__ Tq, u16* __restrict__ Tk,
                       u16* __restrict__ Tv, u16* __restrict__ To) {
  __shared__ float tile[32][33];
  const float* W; u16* T;
  switch (blockIdx.z) {
    case 0:  W = Wq; T = Tq; break;
    case 1:  W = Wk; T = Tk; break;
    case 2:  W = Wv; T = Tv; break;
    default: W = Wo; T = To; break;
  }
  int tx = threadIdx.x, ty = threadIdx.y;
  int n0 = blockIdx.x * 32, k0 = blockIdx.y * 32;
#pragma unroll
  for (int j = 0; j < 4; ++j) tile[ty + j * 8][tx] = W[(k0 + ty + j * 8) * Hc + n0 + tx];
  __syncthreads();
#pragma unroll
  for (int j = 0; j < 4; ++j) T[(n0 + ty + j * 8) * Hc + k0 + tx] = f2bf(tile[tx][ty + j * 8]);
}

// ---------------- GEMM core (C[m][n] = sum_k A[m][k]*Bt[n][k]) ----------------

DI void gemm_core(const u16* __restrict__ Ag, const u16* __restrict__ Btg,
                  u16* Asm, u16* Bsm, int m0, int n0,
                  int tid, int lane, int wr, int wc, f32x4 acc[4][4]) {
  const int lo = lane & 15, hi = lane >> 4;
  const int r1 = tid >> 2, c1 = tid & 3;
  for (int kt = 0; kt < Hc / 32; ++kt) {
    const int k0 = kt * 32;
    {
      int row = r1, cg = c1 ^ ((row >> 1) & 3);
      gload_lds16(Ag  + (size_t)(row + m0) * Hc + k0 + cg * 8, Asm + tid * 8);
      gload_lds16(Btg + (size_t)(row + n0) * Hc + k0 + cg * 8, Bsm + tid * 8);
      row = r1 + 64; cg = c1 ^ ((row >> 1) & 3);
      gload_lds16(Ag  + (size_t)(row + m0) * Hc + k0 + cg * 8, Asm + (tid + 256) * 8);
      gload_lds16(Btg + (size_t)(row + n0) * Hc + k0 + cg * 8, Bsm + (tid + 256) * 8);
    }
    __syncthreads();
    bf16x8 af[4], bf[4];
#pragma unroll
    for (int m = 0; m < 4; ++m) {
      int rowa = wr * 64 + m * 16 + lo;
      af[m] = *reinterpret_cast<const bf16x8*>(Asm + rowa * 32 + ((hi ^ ((rowa >> 1) & 3)) * 8));
      int rowb = wc * 64 + m * 16 + lo;
      bf[m] = *reinterpret_cast<const bf16x8*>(Bsm + rowb * 32 + ((hi ^ ((rowb >> 1) & 3)) * 8));
    }
#pragma unroll
    for (int m = 0; m < 4; ++m)
#pragma unroll
      for (int n = 0; n < 4; ++n)
        acc[m][n] = __builtin_amdgcn_mfma_f32_16x16x32_bf16(af[m], bf[n], acc[m][n], 0, 0, 0);
    __syncthreads();
  }
}

// ---------------- QKV projection ----------------

__launch_bounds__(256)
__global__ void qkv_gemm(const u16* __restrict__ Xb,
                         const u16* __restrict__ Wtq, const u16* __restrict__ Wtk,
                         const u16* __restrict__ Wtv,
                         const float* __restrict__ bq, const float* __restrict__ bk,
                         const float* __restrict__ bv, const int* __restrict__ maskg,
                         u16* __restrict__ Qo, u16* __restrict__ Ko, u16* __restrict__ Vto) {
  __shared__ __attribute__((aligned(16))) u16 Asm[128 * 32];
  __shared__ __attribute__((aligned(16))) u16 Bsm[128 * 32];
  const int tid = threadIdx.x, lane = tid & 63, w = tid >> 6;
  const int wr = w >> 1, wc = w & 1;
  const int m0 = blockIdx.x * 128, n0 = blockIdx.y * 128;
  const int z = blockIdx.z;
  const u16* Bt = (z == 0) ? Wtq : ((z == 1) ? Wtk : Wtv);
  const float* bias = (z == 0) ? bq : ((z == 1) ? bk : bv);
  f32x4 acc[4][4] = {};
  gemm_core(Xb, Bt, Asm, Bsm, m0, n0, tid, lane, wr, wc, acc);
  const int lo = lane & 15, hi = lane >> 4;
  const float scl = (z == 0) ? 0.125f * L2E : 1.0f;    // fold log2(e) into Q
#pragma unroll
  for (int m = 0; m < 4; ++m)
#pragma unroll
    for (int n = 0; n < 4; ++n)
#pragma unroll
      for (int r = 0; r < 4; ++r) {
        int gm = m0 + wr * 64 + m * 16 + hi * 4 + r;
        int gn = n0 + wc * 64 + n * 16 + lo;
        float v = (acc[m][n][r] + bias[gn]) * scl;
        int b = gm >> 11, s = gm & 2047, h = gn >> 6, d = gn & 63;
        if (z == 2) {
          v *= (float)maskg[b * Sc + s];       // zero masked value rows
          int sp = (s & ~12) | ((s & 4) << 1) | ((s & 8) >> 1);   // kv-permute
          Vto[((b * NHc + h) * HDc + d) * Sc + sp] = f2bf(v);
        } else {
          int idx = (((b * NHc + h) * Sc) + s) * HDc + d;
          if (z == 0) Qo[idx] = f2bf(v); else Ko[idx] = f2bf(v);
        }
      }
}

// ---------------- output projection ----------------

__launch_bounds__(256)
__global__ void out_gemm(const u16* __restrict__ Ctx, const u16* __restrict__ Wto,
                         const float* __restrict__ bo, float* __restrict__ out) {
  __shared__ __attribute__((aligned(16))) u16 Asm[128 * 32];
  __shared__ __attribute__((aligned(16))) u16 Bsm[128 * 32];
  const int tid = threadIdx.x, lane = tid & 63, w = tid >> 6;
  const int wr = w >> 1, wc = w & 1;
  const int m0 = blockIdx.x * 128, n0 = blockIdx.y * 128;
  f32x4 acc[4][4] = {};
  gemm_core(Ctx, Wto, Asm, Bsm, m0, n0, tid, lane, wr, wc, acc);
  const int lo = lane & 15, hi = lane >> 4;
#pragma unroll
  for (int m = 0; m < 4; ++m)
#pragma unroll
    for (int n = 0; n < 4; ++n)
#pragma unroll
      for (int r = 0; r < 4; ++r) {
        int gm = m0 + wr * 64 + m * 16 + hi * 4 + r;
        int gn = n0 + wc * 64 + n * 16 + lo;
        out[(size_t)gm * Hc + gn] = acc[m][n][r] + bo[gn];
      }
}

// ---------------- attention helpers (r7-proven forms) ----------------

DI bf16x8 lds_rd(const u16* base, int row, int c8) {       // 8 chunks/row
  return *reinterpret_cast<const bf16x8*>(base + row * 64 + ((c8 ^ (row & 7)) << 3));
}
DI bf16x8 lds_rd4(const u16* base, int row, int c4) {      // 4 chunks/row
  return *reinterpret_cast<const bf16x8*>(base + row * 32 + ((c4 ^ (row & 3)) << 3));
}

DI float vmax16(const f32x16& v) {
  float a0 = fmaxf(v[0], v[8]),  a1 = fmaxf(v[1], v[9]);
  float a2 = fmaxf(v[2], v[10]), a3 = fmaxf(v[3], v[11]);
  float a4 = fmaxf(v[4], v[12]), a5 = fmaxf(v[5], v[13]);
  float a6 = fmaxf(v[6], v[14]), a7 = fmaxf(v[7], v[15]);
  float b0 = fmaxf(a0, a4), b1 = fmaxf(a1, a5);
  float b2 = fmaxf(a2, a6), b3 = fmaxf(a3, a7);
  return fmaxf(fmaxf(b0, b1), fmaxf(b2, b3));
}

DI bf16x8 pkfrag0(const f32x16& p) {
  union { unsigned u[4]; bf16x8 v; } a;
  a.u[0] = f2bf2(p[0], p[1]); a.u[1] = f2bf2(p[2], p[3]);
  a.u[2] = f2bf2(p[4], p[5]); a.u[3] = f2bf2(p[6], p[7]);
  return a.v;
}
DI bf16x8 pkfrag1(const f32x16& p) {
  union { unsigned u[4]; bf16x8 v; } a;
  a.u[0] = f2bf2(p[8], p[9]);   a.u[1] = f2bf2(p[10], p[11]);
  a.u[2] = f2bf2(p[12], p[13]); a.u[3] = f2bf2(p[14], p[15]);
  return a.v;
}

#define ATTN_BAR()  do { __builtin_amdgcn_sched_barrier(0); \
                         __builtin_amdgcn_s_barrier();      \
                         __builtin_amdgcn_sched_barrier(0); } while (0)

// ---------------- attn_full: r7-proven kernel (fallback path) ----------------

__launch_bounds__(128)
__global__ void attn_full(const u16* __restrict__ Qg, const u16* __restrict__ Kg,
                          const u16* __restrict__ Vtg, const u16* __restrict__ monesG,
                          u16* __restrict__ ctxg) {
  __shared__ __attribute__((aligned(16))) u16 Ksm[3][64 * 64];
  __shared__ __attribute__((aligned(16))) u16 Vsm[3][64 * 64];
  __shared__ __attribute__((aligned(16))) u16 Mo[Sc];

  const int tid = threadIdx.x, lane = tid & 63, w = tid >> 6;
  const int l31 = lane & 31, hi2 = lane >> 5;
  const int id = blockIdx.x;
  const int xcd = id & 7, sub = id >> 3;
  const int head = xcd * 3 + (sub >> 5);
  const int q0 = (sub & 31) * 64;
  const int b = head / NHc, h = head % NHc;
  const u16* Qh = Qg + (size_t)head * Sc * HDc;
  const u16* Kh = Kg + (size_t)head * Sc * HDc;
  const u16* Vh = Vtg + (size_t)head * HDc * Sc;

#pragma unroll
  for (int j = 0; j < 2; ++j) {
    int ch = tid + j * 128;
    gload_lds16(monesG + (size_t)b * Sc + ch * 8, Mo + ch * 8);
  }
  const int qglob = q0 + w * 32 + l31;
  bf16x8 qf[4];
#pragma unroll
  for (int c = 0; c < 4; ++c)
    qf[c] = *reinterpret_cast<const bf16x8*>(Qh + (size_t)qglob * HDc + c * 16 + hi2 * 8);
  __syncthreads();

  u16 *K0 = &Ksm[0][0], *K1 = &Ksm[1][0], *K2 = &Ksm[2][0];
  u16 *V0 = &Vsm[0][0], *V1 = &Vsm[1][0], *V2 = &Vsm[2][0];
  auto stage = [&](u16* Kd, u16* Vd, int kv0) {
#pragma unroll
    for (int j = 0; j < 4; ++j) {
      int ch = tid + j * 128;
      int row = ch >> 3, cg = (ch & 7) ^ (row & 7);
      gload_lds16(Kh + (size_t)(kv0 + row) * HDc + cg * 8, Kd + ch * 8);
    }
#pragma unroll
    for (int j = 0; j < 4; ++j) {
      int ch = tid + j * 128;
      int row = ch >> 3, cg = (ch & 7) ^ (row & 7);
      gload_lds16(Vh + (size_t)row * Sc + kv0 + cg * 8, Vd + ch * 8);
    }
  };
  stage(K0, V0, 0);
  stage(K1, V1, 64);

  f32x16 oacc0 = {}, oacc1 = {}, lacc = {};
  float mrow = -1e30f;
  constexpr int NT = Sc / 64;
  for (int t = 0; t < NT; ++t) {
    ATTN_BAR();
    if (t + 2 < NT) {
      stage(K2, V2, (t + 2) * 64);
      asm volatile("s_waitcnt vmcnt(16)" ::: "memory");
    } else if (t + 2 == NT) {
      asm volatile("s_waitcnt vmcnt(8)" ::: "memory");
    } else {
      asm volatile("s_waitcnt vmcnt(0)" ::: "memory");
    }
    ATTN_BAR();
    const u16* Ks = K0;
    const u16* Vs = V0;
    f32x16 s0 = {}, s1 = {};
    __builtin_amdgcn_s_setprio(1);
#pragma unroll
    for (int c = 0; c < 4; ++c) {
      bf16x8 kf0 = lds_rd(Ks, l31, 2 * c + hi2);
      bf16x8 kf1 = lds_rd(Ks, 32 + l31, 2 * c + hi2);
      s0 = __builtin_amdgcn_mfma_f32_32x32x16_bf16(kf0, qf[c], s0, 0, 0, 0);
      s1 = __builtin_amdgcn_mfma_f32_32x32x16_bf16(kf1, qf[c], s1, 0, 0, 0);
    }
    __builtin_amdgcn_s_setprio(0);
    float pmax = fmaxf(vmax16(s0), vmax16(s1));
    pmax = fmaxf(pmax, __shfl_xor(pmax, 32, 64));
    if (!__all(pmax - mrow <= 8.0f)) {
      float nm = fmaxf(mrow, pmax);
      float sc = exp2f(mrow - nm);
      mrow = nm;
#pragma unroll
      for (int rr = 0; rr < 16; ++rr) {
        int qi = (rr & 3) + 8 * (rr >> 2) + 4 * hi2;
        float sb = __shfl(sc, qi, 64);
        oacc0[rr] *= sb; oacc1[rr] *= sb; lacc[rr] *= sb;
      }
    }
#pragma unroll
    for (int j = 0; j < 16; ++j) s0[j] = exp2f(s0[j] - mrow);
#pragma unroll
    for (int j = 0; j < 16; ++j) s1[j] = exp2f(s1[j] - mrow);
    bf16x8 paf[4];
    paf[0] = pkfrag0(s0); paf[1] = pkfrag1(s0);
    paf[2] = pkfrag0(s1); paf[3] = pkfrag1(s1);
    __builtin_amdgcn_s_setprio(1);
#pragma unroll
    for (int c4 = 0; c4 < 4; ++c4) {
      bf16x8 mo = *reinterpret_cast<const bf16x8*>(Mo + t * 64 + c4 * 16 + hi2 * 8);
      bf16x8 vf0 = lds_rd(Vs, l31, 2 * c4 + hi2);
      bf16x8 vf1 = lds_rd(Vs, 32 + l31, 2 * c4 + hi2);
      lacc  = __builtin_amdgcn_mfma_f32_32x32x16_bf16(paf[c4], mo, lacc, 0, 0, 0);
      oacc0 = __builtin_amdgcn_mfma_f32_32x32x16_bf16(paf[c4], vf0, oacc0, 0, 0, 0);
      oacc1 = __builtin_amdgcn_mfma_f32_32x32x16_bf16(paf[c4], vf1, oacc1, 0, 0, 0);
    }
    __builtin_amdgcn_s_setprio(0);
    u16* tk = K0; K0 = K1; K1 = K2; K2 = tk;
    u16* tv = V0; V0 = V1; V1 = V2; V2 = tv;
  }
#pragma unroll
  for (int rr = 0; rr < 16; ++rr) {
    float inv = 1.0f / lacc[rr];
    int qi = (rr & 3) + 8 * (rr >> 2) + 4 * hi2;
    int s = q0 + w * 32 + qi;
    size_t base = (size_t)(b * Sc + s) * Hc + h * HDc;
    ctxg[base + l31]      = f2bf(oacc0[rr] * inv);
    ctxg[base + 32 + l31] = f2bf(oacc1[rr] * inv);
  }
}

// ---------------- attn_split: kv-split x2, KVBLK=32, 26KB LDS -> 6 blk/CU ---
// 1536 blocks: xcd=id&7, sub=id>>3; head=xcd*3+sub/64; r=sub&63;
// q0=(r>>1)*64; kh=r&1 (kv half). Emits f32 partials (o, l, m); combine
// kernel merges the two halves exactly (softmax is m-shift invariant).

__launch_bounds__(128)
__global__ void attn_split(const u16* __restrict__ Qg, const u16* __restrict__ Kg,
                           const u16* __restrict__ Vtg, const u16* __restrict__ monesG,
                           float* __restrict__ Po, float* __restrict__ Pl,
                           float* __restrict__ Pm) {
  __shared__ __attribute__((aligned(16))) u16 Ksm[3][32 * 64];
  __shared__ __attribute__((aligned(16))) u16 Vsm[3][64 * 32];
  __shared__ __attribute__((aligned(16))) u16 Mo[1024];

  const int tid = threadIdx.x, lane = tid & 63, w = tid >> 6;
  const int l31 = lane & 31, hi2 = lane >> 5;
  const int id = blockIdx.x;
  const int xcd = id & 7, sub = id >> 3;          // sub 0..191
  const int head = xcd * 3 + (sub >> 6);          // 3 heads/XCD
  const int r = sub & 63;
  const int q0 = (r >> 1) * 64;
  const int kh = r & 1;
  const int b = head / NHc;
  const int kvbase = kh * 1024;

  const u16* Qh = Qg + (size_t)head * Sc * HDc;
  const u16* Kh = Kg + (size_t)head * Sc * HDc;
  const u16* Vh = Vtg + (size_t)head * HDc * Sc;

  // maskones half (pre-permuted)
  gload_lds16(monesG + (size_t)b * Sc + kvbase + tid * 8, Mo + tid * 8);

  const int qglob = q0 + w * 32 + l31;
  bf16x8 qf[4];
#pragma unroll
  for (int c = 0; c < 4; ++c)
    qf[c] = *reinterpret_cast<const bf16x8*>(Qh + (size_t)qglob * HDc + c * 16 + hi2 * 8);
  __syncthreads();                                // drain Q + Mo vmem

  u16 *K0 = &Ksm[0][0], *K1 = &Ksm[1][0], *K2 = &Ksm[2][0];
  u16 *V0 = &Vsm[0][0], *V1 = &Vsm[1][0], *V2 = &Vsm[2][0];

  // per-thread staging: 2 K chunks + 2 V chunks (4 vmem ops/thread)
  auto stage = [&](u16* Kd, u16* Vd, int kv0) {
#pragma unroll
    for (int j = 0; j < 2; ++j) {
      int ch = tid + j * 128;                     // 0..255
      int row = ch >> 3, cg = (ch & 7) ^ (row & 7);   // 32 rows x 8 chunks
      gload_lds16(Kh + (size_t)(kv0 + row) * HDc + cg * 8, Kd + ch * 8);
    }
#pragma unroll
    for (int j = 0; j < 2; ++j) {
      int ch = tid + j * 128;
      int row = ch >> 2, cg = (ch & 3) ^ (row & 3);   // 64 rows x 4 chunks
      gload_lds16(Vh + (size_t)row * Sc + kv0 + cg * 8, Vd + ch * 8);
    }
  };
  stage(K0, V0, kvbase);
  stage(K1, V1, kvbase + 32);

  f32x16 oacc0 = {}, oacc1 = {}, lacc = {};
  float mrow = -1e30f;
  constexpr int NT = 32;                          // 1024 kv / 32
  for (int t = 0; t < NT; ++t) {
    ATTN_BAR();                                   // write-safety
    if (t + 2 < NT) {
      stage(K2, V2, kvbase + (t + 2) * 32);
      asm volatile("s_waitcnt vmcnt(8)" ::: "memory");    // tile t resident
    } else if (t + 2 == NT) {
      asm volatile("s_waitcnt vmcnt(4)" ::: "memory");
    } else {
      asm volatile("s_waitcnt vmcnt(0)" ::: "memory");
    }
    ATTN_BAR();                                   // read-safety
    const u16* Ks = K0;
    const u16* Vs = V0;

    // QK^T swapped: 32 kv rows; lane owns q = l31
    f32x16 s0 = {};
    __builtin_amdgcn_s_setprio(1);
#pragma unroll
    for (int c = 0; c < 4; ++c) {
      bf16x8 kf = lds_rd(Ks, l31, 2 * c + hi2);
      s0 = __builtin_amdgcn_mfma_f32_32x32x16_bf16(kf, qf[c], s0, 0, 0, 0);
    }
    __builtin_amdgcn_s_setprio(0);

    float pmax = vmax16(s0);
    pmax = fmaxf(pmax, __shfl_xor(pmax, 32, 64));
    if (!__all(pmax - mrow <= 8.0f)) {
      float nm = fmaxf(mrow, pmax);
      float sc = exp2f(mrow - nm);
      mrow = nm;
#pragma unroll
      for (int rr = 0; rr < 16; ++rr) {
        int qi = (rr & 3) + 8 * (rr >> 2) + 4 * hi2;
        float sb = __shfl(sc, qi, 64);
        oacc0[rr] *= sb; oacc1[rr] *= sb; lacc[rr] *= sb;
      }
    }
#pragma unroll
    for (int j = 0; j < 16; ++j) s0[j] = exp2f(s0[j] - mrow);

    bf16x8 paf0 = pkfrag0(s0), paf1 = pkfrag1(s0);

    __builtin_amdgcn_s_setprio(1);
#pragma unroll
    for (int c4 = 0; c4 < 2; ++c4) {
      bf16x8 pa = c4 ? paf1 : paf0;
      bf16x8 mo = *reinterpret_cast<const bf16x8*>(Mo + t * 32 + c4 * 16 + hi2 * 8);
      bf16x8 vf0 = lds_rd4(Vs, l31, 2 * c4 + hi2);
      bf16x8 vf1 = lds_rd4(Vs, 32 + l31, 2 * c4 + hi2);
      lacc  = __builtin_amdgcn_mfma_f32_32x32x16_bf16(pa, mo, lacc, 0, 0, 0);
      oacc0 = __builtin_amdgcn_mfma_f32_32x32x16_bf16(pa, vf0, oacc0, 0, 0, 0);
      oacc1 = __builtin_amdgcn_mfma_f32_32x32x16_bf16(pa, vf1, oacc1, 0, 0, 0);
    }
    __builtin_amdgcn_s_setprio(0);

    u16* tk = K0; K0 = K1; K1 = K2; K2 = tk;
    u16* tv = V0; V0 = V1; V1 = V2; V2 = tv;
  }

  // partial epilogue: NO division; write o (f32), l, m
  const size_t pbase = ((size_t)(kh * 24 + head)) * Sc;
#pragma unroll
  for (int rr = 0; rr < 16; ++rr) {
    int qi = (rr & 3) + 8 * (rr >> 2) + 4 * hi2;
    int q = q0 + w * 32 + qi;
    float* dst = Po + (pbase + q) * HDc;
    dst[l31]      = oacc0[rr];
    dst[32 + l31] = oacc1[rr];
  }
  if (l31 == 0) {                                 // lanes 0 and 32
#pragma unroll
    for (int rr = 0; rr < 16; ++rr) {
      int qi = (rr & 3) + 8 * (rr >> 2) + 4 * hi2;
      Pl[pbase + q0 + w * 32 + qi] = lacc[rr];
    }
  }
  if (hi2 == 0) Pm[pbase + q0 + w * 32 + l31] = mrow;
}

// ---------------- combine: merge the two kv-halves exactly ----------------

__global__ void combine(const float* __restrict__ Po, const float* __restrict__ Pl,
                        const float* __restrict__ Pm, u16* __restrict__ ctxg) {
  int idx = blockIdx.x * 256 + threadIdx.x;       // 24*2048*16
  int head = idx >> 15;
  int rem = idx & 32767;
  int q = rem >> 4, d4 = rem & 15;
  size_t hq = (size_t)head * Sc + q;
  const size_t HSTR = (size_t)24 * Sc;            // kh stride for l/m
  float m0 = Pm[hq], m1 = Pm[HSTR + hq];
  float l0 = Pl[hq], l1 = Pl[HSTR + hq];
  float M = fmaxf(m0, m1);
  float e0 = exp2f(m0 - M), e1 = exp2f(m1 - M);
  float inv = 1.0f / (l0 * e0 + l1 * e1);
  const float4* P4 = reinterpret_cast<const float4*>(Po);
  float4 o0 = P4[hq * 16 + d4];
  float4 o1 = P4[(HSTR + hq) * 16 + d4];
  u16x4 pk;
  pk[0] = f2bf((o0.x * e0 + o1.x * e1) * inv);
  pk[1] = f2bf((o0.y * e0 + o1.y * e1) * inv);
  pk[2] = f2bf((o0.z * e0 + o1.z * e1) * inv);
  pk[3] = f2bf((o0.w * e0 + o1.w * e1) * inv);
  int b = head / NHc, h = head - b * NHc;
  *reinterpret_cast<u16x4*>(ctxg + (size_t)(b * Sc + q) * Hc + h * HDc + d4 * 4) = pk;
}

// ---------------- launch ----------------

extern "C" void kernel_launch(void* const* d_in, const int* in_sizes, int n_in,
                              void* d_out, int out_size, void* d_ws, size_t ws_size,
                              hipStream_t stream) {
  const float* hs  = (const float*)d_in[0];
  const int* mask  = (const int*)d_in[1];
  const float* Wq  = (const float*)d_in[2];
  const float* bq  = (const float*)d_in[3];
  const float* Wk  = (const float*)d_in[4];
  const float* bk  = (const float*)d_in[5];
  const float* Wv  = (const float*)d_in[6];
  const float* bv  = (const float*)d_in[7];
  const float* Wo  = (const float*)d_in[8];
  const float* bo  = (const float*)d_in[9];

  char* ws = (char*)d_ws;
  u16* Xb  = (u16*)(ws);                      // 4096x768 bf16
  u16* Wtq = (u16*)(ws + 6291456);            // 4x 768x768 bf16
  u16* Wtk = Wtq + 589824;
  u16* Wtv = Wtk + 589824;
  u16* Wto = Wtv + 589824;
  u16* Qb  = (u16*)(ws + 11010048);           // [24][2048][64]
  u16* Kb  = Qb + 3145728;                    // [24][2048][64]
  u16* Vtb = Kb + 3145728;                    // [24][64][2048] (kv-permuted)
  u16* Ctx = Vtb + 3145728;                   // 4096x768 bf16
  u16* Mns = Ctx + 3145728;                   // [2][2048] maskones (perm)
  // split-path partials (past byte 36,184,064)
  float* Po = (float*)(ws + 36184064);        // [2][24][2048][64] f32, 25.2MB
  float* Pl = (float*)(ws + 61349888);        // [2][24][2048] f32
  float* Pm = (float*)(ws + 61743104);        // [2][24][2048] f32 -> end 62,136,320
  const bool use_split = ws_size >= 62136320ull;

  cvt_bf16<<<(Mc * Hc / 4 + 255) / 256, 256, 0, stream>>>(hs, Xb, Mc * Hc / 4, mask, Mns);
  wtrans<<<dim3(24, 24, 4), dim3(32, 8), 0, stream>>>(Wq, Wk, Wv, Wo, Wtq, Wtk, Wtv, Wto);
  qkv_gemm<<<dim3(32, 6, 3), 256, 0, stream>>>(Xb, Wtq, Wtk, Wtv, bq, bk, bv, mask, Qb, Kb, Vtb);
  if (use_split) {
    attn_split<<<1536, 128, 0, stream>>>(Qb, Kb, Vtb, Mns, Po, Pl, Pm);
    combine<<<3072, 256, 0, stream>>>(Po, Pl, Pm, Ctx);
  } else {
    attn_full<<<768, 128, 0, stream>>>(Qb, Kb, Vtb, Mns, Ctx);
  }
  out_gemm<<<dim3(32, 6), 256, 0, stream>>>(Ctx, Wto, bo, (float*)d_out);
}

// Round 10
// 159.087 us; speedup vs baseline: 1.0030x; 1.0030x over previous
//
#include <hip/hip_runtime.h>
#include <hip/hip_bf16.h>

#define DI __device__ __forceinline__

using bf16x8 = __attribute__((ext_vector_type(8))) short;
using f32x4  = __attribute__((ext_vector_type(4))) float;
using f32x16 = __attribute__((ext_vector_type(16))) float;
using u16    = unsigned short;
using u16x4  = __attribute__((ext_vector_type(4))) unsigned short;

constexpr int Bc = 2, Sc = 2048, Hc = 768, NHc = 12, HDc = 64;
constexpr int Mc = Bc * Sc;                 // 4096 rows
constexpr float L2E = 1.4426950408889634f;

DI u16 f2bf(float f) {
  union { float f; unsigned u; } c; c.f = f;
  unsigned u = c.u;
  return (u16)((u + 0x7fffu + ((u >> 16) & 1u)) >> 16);   // RNE
}

DI unsigned f2bf2(float a, float b) {
  float2 t; t.x = a; t.y = b;
  __hip_bfloat162 h = __float22bfloat162_rn(t);
  union { __hip_bfloat162 h; unsigned u; } c; c.h = h;
  return c.u;
}

DI void gload_lds16(const void* g, void* l) {
  __builtin_amdgcn_global_load_lds(
      (__attribute__((address_space(1))) void*)(g),
      (__attribute__((address_space(3))) void*)(l), 16, 0, 0);
}

// ---------------- prep kernels ----------------

// also converts mask -> maskones bf16, PERMUTED within 16-groups (swap kv
// bits 2<->3) so attn's PV B-frag slots are one contiguous 16B chunk.
__global__ void cvt_bf16(const float* __restrict__ x, u16* __restrict__ y, int n4,
                         const int* __restrict__ maskg, u16* __restrict__ mones) {
  int i = blockIdx.x * 256 + threadIdx.x;
  if (i >= n4) return;
  float4 v = reinterpret_cast<const float4*>(x)[i];
  u16x4 o;
  o[0] = f2bf(v.x); o[1] = f2bf(v.y); o[2] = f2bf(v.z); o[3] = f2bf(v.w);
  reinterpret_cast<u16x4*>(y)[i] = o;
  if (i < Bc * Sc / 4) {
    int j = i & 3;
    int js = ((j & 1) << 1) | ((j >> 1) & 1);      // swap bits within quad
    int isrc = (i & ~3) | js;
    int4 mv = reinterpret_cast<const int4*>(maskg)[isrc];
    u16x4 m;
    m[0] = f2bf((float)mv.x); m[1] = f2bf((float)mv.y);
    m[2] = f2bf((float)mv.z); m[3] = f2bf((float)mv.w);
    reinterpret_cast<u16x4*>(mones)[i] = m;
  }
}

// Wt[n][k] = W[k][n], bf16
__global__ void wtrans(const float* __restrict__ Wq, const float* __restrict__ Wk,
                       const float* __restrict__ Wv, const float* __restrict__ Wo,
                       u16* __restrict__ Tq, u16* __restrict__ Tk,
                       u16* __restrict__ Tv, u16* __restrict__ To) {
  __shared__ float tile[32][33];
  const float* W; u16* T;
  switch (blockIdx.z) {
    case 0:  W = Wq; T = Tq; break;
    case 1:  W = Wk; T = Tk; break;
    case 2:  W = Wv; T = Tv; break;
    default: W = Wo; T = To; break;
  }
  int tx = threadIdx.x, ty = threadIdx.y;
  int n0 = blockIdx.x * 32, k0 = blockIdx.y * 32;
#pragma unroll
  for (int j = 0; j < 4; ++j) tile[ty + j * 8][tx] = W[(k0 + ty + j * 8) * Hc + n0 + tx];
  __syncthreads();
#pragma unroll
  for (int j = 0; j < 4; ++j) T[(n0 + ty + j * 8) * Hc + k0 + tx] = f2bf(tile[tx][ty + j * 8]);
}

// ---------------- GEMM core (C[m][n] = sum_k A[m][k]*Bt[n][k]) ----------------

DI void gemm_core(const u16* __restrict__ Ag, const u16* __restrict__ Btg,
                  u16* Asm, u16* Bsm, int m0, int n0,
                  int tid, int lane, int wr, int wc, f32x4 acc[4][4]) {
  const int lo = lane & 15, hi = lane >> 4;
  const int r1 = tid >> 2, c1 = tid & 3;
  for (int kt = 0; kt < Hc / 32; ++kt) {
    const int k0 = kt * 32;
    {
      int row = r1, cg = c1 ^ ((row >> 1) & 3);
      gload_lds16(Ag  + (size_t)(row + m0) * Hc + k0 + cg * 8, Asm + tid * 8);
      gload_lds16(Btg + (size_t)(row + n0) * Hc + k0 + cg * 8, Bsm + tid * 8);
      row = r1 + 64; cg = c1 ^ ((row >> 1) & 3);
      gload_lds16(Ag  + (size_t)(row + m0) * Hc + k0 + cg * 8, Asm + (tid + 256) * 8);
      gload_lds16(Btg + (size_t)(row + n0) * Hc + k0 + cg * 8, Bsm + (tid + 256) * 8);
    }
    __syncthreads();
    bf16x8 af[4], bf[4];
#pragma unroll
    for (int m = 0; m < 4; ++m) {
      int rowa = wr * 64 + m * 16 + lo;
      af[m] = *reinterpret_cast<const bf16x8*>(Asm + rowa * 32 + ((hi ^ ((rowa >> 1) & 3)) * 8));
      int rowb = wc * 64 + m * 16 + lo;
      bf[m] = *reinterpret_cast<const bf16x8*>(Bsm + rowb * 32 + ((hi ^ ((rowb >> 1) & 3)) * 8));
    }
#pragma unroll
    for (int m = 0; m < 4; ++m)
#pragma unroll
      for (int n = 0; n < 4; ++n)
        acc[m][n] = __builtin_amdgcn_mfma_f32_16x16x32_bf16(af[m], bf[n], acc[m][n], 0, 0, 0);
    __syncthreads();
  }
}

// ---------------- QKV projection ----------------

__launch_bounds__(256)
__global__ void qkv_gemm(const u16* __restrict__ Xb,
                         const u16* __restrict__ Wtq, const u16* __restrict__ Wtk,
                         const u16* __restrict__ Wtv,
                         const float* __restrict__ bq, const float* __restrict__ bk,
                         const float* __restrict__ bv, const int* __restrict__ maskg,
                         u16* __restrict__ Qo, u16* __restrict__ Ko, u16* __restrict__ Vto) {
  __shared__ __attribute__((aligned(16))) u16 Asm[128 * 32];
  __shared__ __attribute__((aligned(16))) u16 Bsm[128 * 32];
  const int tid = threadIdx.x, lane = tid & 63, w = tid >> 6;
  const int wr = w >> 1, wc = w & 1;
  const int m0 = blockIdx.x * 128, n0 = blockIdx.y * 128;
  const int z = blockIdx.z;
  const u16* Bt = (z == 0) ? Wtq : ((z == 1) ? Wtk : Wtv);
  const float* bias = (z == 0) ? bq : ((z == 1) ? bk : bv);
  f32x4 acc[4][4] = {};
  gemm_core(Xb, Bt, Asm, Bsm, m0, n0, tid, lane, wr, wc, acc);
  const int lo = lane & 15, hi = lane >> 4;
  const float scl = (z == 0) ? 0.125f * L2E : 1.0f;    // fold log2(e) into Q
#pragma unroll
  for (int m = 0; m < 4; ++m)
#pragma unroll
    for (int n = 0; n < 4; ++n)
#pragma unroll
      for (int r = 0; r < 4; ++r) {
        int gm = m0 + wr * 64 + m * 16 + hi * 4 + r;
        int gn = n0 + wc * 64 + n * 16 + lo;
        float v = (acc[m][n][r] + bias[gn]) * scl;
        int b = gm >> 11, s = gm & 2047, h = gn >> 6, d = gn & 63;
        if (z == 2) {
          v *= (float)maskg[b * Sc + s];       // zero masked value rows
          int sp = (s & ~12) | ((s & 4) << 1) | ((s & 8) >> 1);   // kv-permute
          Vto[((b * NHc + h) * HDc + d) * Sc + sp] = f2bf(v);
        } else {
          int idx = (((b * NHc + h) * Sc) + s) * HDc + d;
          if (z == 0) Qo[idx] = f2bf(v); else Ko[idx] = f2bf(v);
        }
      }
}

// ---------------- output projection ----------------

__launch_bounds__(256)
__global__ void out_gemm(const u16* __restrict__ Ctx, const u16* __restrict__ Wto,
                         const float* __restrict__ bo, float* __restrict__ out) {
  __shared__ __attribute__((aligned(16))) u16 Asm[128 * 32];
  __shared__ __attribute__((aligned(16))) u16 Bsm[128 * 32];
  const int tid = threadIdx.x, lane = tid & 63, w = tid >> 6;
  const int wr = w >> 1, wc = w & 1;
  const int m0 = blockIdx.x * 128, n0 = blockIdx.y * 128;
  f32x4 acc[4][4] = {};
  gemm_core(Ctx, Wto, Asm, Bsm, m0, n0, tid, lane, wr, wc, acc);
  const int lo = lane & 15, hi = lane >> 4;
#pragma unroll
  for (int m = 0; m < 4; ++m)
#pragma unroll
    for (int n = 0; n < 4; ++n)
#pragma unroll
      for (int r = 0; r < 4; ++r) {
        int gm = m0 + wr * 64 + m * 16 + hi * 4 + r;
        int gn = n0 + wc * 64 + n * 16 + lo;
        out[(size_t)gm * Hc + gn] = acc[m][n][r] + bo[gn];
      }
}

// ---------------- attention helpers (r7-proven forms) ----------------

DI bf16x8 lds_rd(const u16* base, int row, int c8) {       // 8 chunks/row
  return *reinterpret_cast<const bf16x8*>(base + row * 64 + ((c8 ^ (row & 7)) << 3));
}
DI bf16x8 lds_rd4(const u16* base, int row, int c4) {      // 4 chunks/row
  return *reinterpret_cast<const bf16x8*>(base + row * 32 + ((c4 ^ (row & 3)) << 3));
}

DI float vmax16(const f32x16& v) {
  float a0 = fmaxf(v[0], v[8]),  a1 = fmaxf(v[1], v[9]);
  float a2 = fmaxf(v[2], v[10]), a3 = fmaxf(v[3], v[11]);
  float a4 = fmaxf(v[4], v[12]), a5 = fmaxf(v[5], v[13]);
  float a6 = fmaxf(v[6], v[14]), a7 = fmaxf(v[7], v[15]);
  float b0 = fmaxf(a0, a4), b1 = fmaxf(a1, a5);
  float b2 = fmaxf(a2, a6), b3 = fmaxf(a3, a7);
  return fmaxf(fmaxf(b0, b1), fmaxf(b2, b3));
}

DI bf16x8 pkfrag0(const f32x16& p) {
  union { unsigned u[4]; bf16x8 v; } a;
  a.u[0] = f2bf2(p[0], p[1]); a.u[1] = f2bf2(p[2], p[3]);
  a.u[2] = f2bf2(p[4], p[5]); a.u[3] = f2bf2(p[6], p[7]);
  return a.v;
}
DI bf16x8 pkfrag1(const f32x16& p) {
  union { unsigned u[4]; bf16x8 v; } a;
  a.u[0] = f2bf2(p[8], p[9]);   a.u[1] = f2bf2(p[10], p[11]);
  a.u[2] = f2bf2(p[12], p[13]); a.u[3] = f2bf2(p[14], p[15]);
  return a.v;
}

#define ATTN_BAR()  do { __builtin_amdgcn_sched_barrier(0); \
                         __builtin_amdgcn_s_barrier();      \
                         __builtin_amdgcn_sched_barrier(0); } while (0)

// ---------------- attn_full: r7-proven kernel (fallback path) ----------------

__launch_bounds__(128)
__global__ void attn_full(const u16* __restrict__ Qg, const u16* __restrict__ Kg,
                          const u16* __restrict__ Vtg, const u16* __restrict__ monesG,
                          u16* __restrict__ ctxg) {
  __shared__ __attribute__((aligned(16))) u16 Ksm[3][64 * 64];
  __shared__ __attribute__((aligned(16))) u16 Vsm[3][64 * 64];
  __shared__ __attribute__((aligned(16))) u16 Mo[Sc];

  const int tid = threadIdx.x, lane = tid & 63, w = tid >> 6;
  const int l31 = lane & 31, hi2 = lane >> 5;
  const int id = blockIdx.x;
  const int xcd = id & 7, sub = id >> 3;
  const int head = xcd * 3 + (sub >> 5);
  const int q0 = (sub & 31) * 64;
  const int b = head / NHc, h = head % NHc;
  const u16* Qh = Qg + (size_t)head * Sc * HDc;
  const u16* Kh = Kg + (size_t)head * Sc * HDc;
  const u16* Vh = Vtg + (size_t)head * HDc * Sc;

#pragma unroll
  for (int j = 0; j < 2; ++j) {
    int ch = tid + j * 128;
    gload_lds16(monesG + (size_t)b * Sc + ch * 8, Mo + ch * 8);
  }
  const int qglob = q0 + w * 32 + l31;
  bf16x8 qf[4];
#pragma unroll
  for (int c = 0; c < 4; ++c)
    qf[c] = *reinterpret_cast<const bf16x8*>(Qh + (size_t)qglob * HDc + c * 16 + hi2 * 8);
  __syncthreads();

  u16 *K0 = &Ksm[0][0], *K1 = &Ksm[1][0], *K2 = &Ksm[2][0];
  u16 *V0 = &Vsm[0][0], *V1 = &Vsm[1][0], *V2 = &Vsm[2][0];
  auto stage = [&](u16* Kd, u16* Vd, int kv0) {
#pragma unroll
    for (int j = 0; j < 4; ++j) {
      int ch = tid + j * 128;
      int row = ch >> 3, cg = (ch & 7) ^ (row & 7);
      gload_lds16(Kh + (size_t)(kv0 + row) * HDc + cg * 8, Kd + ch * 8);
    }
#pragma unroll
    for (int j = 0; j < 4; ++j) {
      int ch = tid + j * 128;
      int row = ch >> 3, cg = (ch & 7) ^ (row & 7);
      gload_lds16(Vh + (size_t)row * Sc + kv0 + cg * 8, Vd + ch * 8);
    }
  };
  stage(K0, V0, 0);
  stage(K1, V1, 64);

  f32x16 oacc0 = {}, oacc1 = {}, lacc = {};
  float mrow = -1e30f;
  constexpr int NT = Sc / 64;
  for (int t = 0; t < NT; ++t) {
    ATTN_BAR();
    if (t + 2 < NT) {
      stage(K2, V2, (t + 2) * 64);
      asm volatile("s_waitcnt vmcnt(16)" ::: "memory");
    } else if (t + 2 == NT) {
      asm volatile("s_waitcnt vmcnt(8)" ::: "memory");
    } else {
      asm volatile("s_waitcnt vmcnt(0)" ::: "memory");
    }
    ATTN_BAR();
    const u16* Ks = K0;
    const u16* Vs = V0;
    f32x16 s0 = {}, s1 = {};
    __builtin_amdgcn_s_setprio(1);
#pragma unroll
    for (int c = 0; c < 4; ++c) {
      bf16x8 kf0 = lds_rd(Ks, l31, 2 * c + hi2);
      bf16x8 kf1 = lds_rd(Ks, 32 + l31, 2 * c + hi2);
      s0 = __builtin_amdgcn_mfma_f32_32x32x16_bf16(kf0, qf[c], s0, 0, 0, 0);
      s1 = __builtin_amdgcn_mfma_f32_32x32x16_bf16(kf1, qf[c], s1, 0, 0, 0);
    }
    __builtin_amdgcn_s_setprio(0);
    float pmax = fmaxf(vmax16(s0), vmax16(s1));
    pmax = fmaxf(pmax, __shfl_xor(pmax, 32, 64));
    if (!__all(pmax - mrow <= 8.0f)) {
      float nm = fmaxf(mrow, pmax);
      float sc = exp2f(mrow - nm);
      mrow = nm;
#pragma unroll
      for (int rr = 0; rr < 16; ++rr) {
        int qi = (rr & 3) + 8 * (rr >> 2) + 4 * hi2;
        float sb = __shfl(sc, qi, 64);
        oacc0[rr] *= sb; oacc1[rr] *= sb; lacc[rr] *= sb;
      }
    }
#pragma unroll
    for (int j = 0; j < 16; ++j) s0[j] = exp2f(s0[j] - mrow);
#pragma unroll
    for (int j = 0; j < 16; ++j) s1[j] = exp2f(s1[j] - mrow);
    bf16x8 paf[4];
    paf[0] = pkfrag0(s0); paf[1] = pkfrag1(s0);
    paf[2] = pkfrag0(s1); paf[3] = pkfrag1(s1);
    __builtin_amdgcn_s_setprio(1);
#pragma unroll
    for (int c4 = 0; c4 < 4; ++c4) {
      bf16x8 mo = *reinterpret_cast<const bf16x8*>(Mo + t * 64 + c4 * 16 + hi2 * 8);
      bf16x8 vf0 = lds_rd(Vs, l31, 2 * c4 + hi2);
      bf16x8 vf1 = lds_rd(Vs, 32 + l31, 2 * c4 + hi2);
      lacc  = __builtin_amdgcn_mfma_f32_32x32x16_bf16(paf[c4], mo, lacc, 0, 0, 0);
      oacc0 = __builtin_amdgcn_mfma_f32_32x32x16_bf16(paf[c4], vf0, oacc0, 0, 0, 0);
      oacc1 = __builtin_amdgcn_mfma_f32_32x32x16_bf16(paf[c4], vf1, oacc1, 0, 0, 0);
    }
    __builtin_amdgcn_s_setprio(0);
    u16* tk = K0; K0 = K1; K1 = K2; K2 = tk;
    u16* tv = V0; V0 = V1; V1 = V2; V2 = tv;
  }
#pragma unroll
  for (int rr = 0; rr < 16; ++rr) {
    float inv = 1.0f / lacc[rr];
    int qi = (rr & 3) + 8 * (rr >> 2) + 4 * hi2;
    int s = q0 + w * 32 + qi;
    size_t base = (size_t)(b * Sc + s) * Hc + h * HDc;
    ctxg[base + l31]      = f2bf(oacc0[rr] * inv);
    ctxg[base + 32 + l31] = f2bf(oacc1[rr] * inv);
  }
}

// ---------------- attn_split: kv-split x2, KVBLK=32, 26KB LDS -> 6 blk/CU ---
// 1536 blocks: xcd=id&7, sub=id>>3; head=xcd*3+sub/64; r=sub&63;
// q0=(r>>1)*64; kh=r&1 (kv half). Emits f32 partials (o, l, m); combine
// kernel merges the two halves exactly (softmax is m-shift invariant).

__launch_bounds__(128)
__global__ void attn_split(const u16* __restrict__ Qg, const u16* __restrict__ Kg,
                           const u16* __restrict__ Vtg, const u16* __restrict__ monesG,
                           float* __restrict__ Po, float* __restrict__ Pl,
                           float* __restrict__ Pm) {
  __shared__ __attribute__((aligned(16))) u16 Ksm[3][32 * 64];
  __shared__ __attribute__((aligned(16))) u16 Vsm[3][64 * 32];
  __shared__ __attribute__((aligned(16))) u16 Mo[1024];

  const int tid = threadIdx.x, lane = tid & 63, w = tid >> 6;
  const int l31 = lane & 31, hi2 = lane >> 5;
  const int id = blockIdx.x;
  const int xcd = id & 7, sub = id >> 3;          // sub 0..191
  const int head = xcd * 3 + (sub >> 6);          // 3 heads/XCD
  const int r = sub & 63;
  const int q0 = (r >> 1) * 64;
  const int kh = r & 1;
  const int b = head / NHc;
  const int kvbase = kh * 1024;

  const u16* Qh = Qg + (size_t)head * Sc * HDc;
  const u16* Kh = Kg + (size_t)head * Sc * HDc;
  const u16* Vh = Vtg + (size_t)head * HDc * Sc;

  // maskones half (pre-permuted)
  gload_lds16(monesG + (size_t)b * Sc + kvbase + tid * 8, Mo + tid * 8);

  const int qglob = q0 + w * 32 + l31;
  bf16x8 qf[4];
#pragma unroll
  for (int c = 0; c < 4; ++c)
    qf[c] = *reinterpret_cast<const bf16x8*>(Qh + (size_t)qglob * HDc + c * 16 + hi2 * 8);
  __syncthreads();                                // drain Q + Mo vmem

  u16 *K0 = &Ksm[0][0], *K1 = &Ksm[1][0], *K2 = &Ksm[2][0];
  u16 *V0 = &Vsm[0][0], *V1 = &Vsm[1][0], *V2 = &Vsm[2][0];

  // per-thread staging: 2 K chunks + 2 V chunks (4 vmem ops/thread)
  auto stage = [&](u16* Kd, u16* Vd, int kv0) {
#pragma unroll
    for (int j = 0; j < 2; ++j) {
      int ch = tid + j * 128;                     // 0..255
      int row = ch >> 3, cg = (ch & 7) ^ (row & 7);   // 32 rows x 8 chunks
      gload_lds16(Kh + (size_t)(kv0 + row) * HDc + cg * 8, Kd + ch * 8);
    }
#pragma unroll
    for (int j = 0; j < 2; ++j) {
      int ch = tid + j * 128;
      int row = ch >> 2, cg = (ch & 3) ^ (row & 3);   // 64 rows x 4 chunks
      gload_lds16(Vh + (size_t)row * Sc + kv0 + cg * 8, Vd + ch * 8);
    }
  };
  stage(K0, V0, kvbase);
  stage(K1, V1, kvbase + 32);

  f32x16 oacc0 = {}, oacc1 = {}, lacc = {};
  float mrow = -1e30f;
  constexpr int NT = 32;                          // 1024 kv / 32
  for (int t = 0; t < NT; ++t) {
    ATTN_BAR();                                   // write-safety
    if (t + 2 < NT) {
      stage(K2, V2, kvbase + (t + 2) * 32);
      asm volatile("s_waitcnt vmcnt(8)" ::: "memory");    // tile t resident
    } else if (t + 2 == NT) {
      asm volatile("s_waitcnt vmcnt(4)" ::: "memory");
    } else {
      asm volatile("s_waitcnt vmcnt(0)" ::: "memory");
    }
    ATTN_BAR();                                   // read-safety
    const u16* Ks = K0;
    const u16* Vs = V0;

    // QK^T swapped: 32 kv rows; lane owns q = l31
    f32x16 s0 = {};
    __builtin_amdgcn_s_setprio(1);
#pragma unroll
    for (int c = 0; c < 4; ++c) {
      bf16x8 kf = lds_rd(Ks, l31, 2 * c + hi2);
      s0 = __builtin_amdgcn_mfma_f32_32x32x16_bf16(kf, qf[c], s0, 0, 0, 0);
    }
    __builtin_amdgcn_s_setprio(0);

    float pmax = vmax16(s0);
    pmax = fmaxf(pmax, __shfl_xor(pmax, 32, 64));
    if (!__all(pmax - mrow <= 8.0f)) {
      float nm = fmaxf(mrow, pmax);
      float sc = exp2f(mrow - nm);
      mrow = nm;
#pragma unroll
      for (int rr = 0; rr < 16; ++rr) {
        int qi = (rr & 3) + 8 * (rr >> 2) + 4 * hi2;
        float sb = __shfl(sc, qi, 64);
        oacc0[rr] *= sb; oacc1[rr] *= sb; lacc[rr] *= sb;
      }
    }
#pragma unroll
    for (int j = 0; j < 16; ++j) s0[j] = exp2f(s0[j] - mrow);

    bf16x8 paf0 = pkfrag0(s0), paf1 = pkfrag1(s0);

    __builtin_amdgcn_s_setprio(1);
#pragma unroll
    for (int c4 = 0; c4 < 2; ++c4) {
      bf16x8 pa = c4 ? paf1 : paf0;
      bf16x8 mo = *reinterpret_cast<const bf16x8*>(Mo + t * 32 + c4 * 16 + hi2 * 8);
      bf16x8 vf0 = lds_rd4(Vs, l31, 2 * c4 + hi2);
      bf16x8 vf1 = lds_rd4(Vs, 32 + l31, 2 * c4 + hi2);
      lacc  = __builtin_amdgcn_mfma_f32_32x32x16_bf16(pa, mo, lacc, 0, 0, 0);
      oacc0 = __builtin_amdgcn_mfma_f32_32x32x16_bf16(pa, vf0, oacc0, 0, 0, 0);
      oacc1 = __builtin_amdgcn_mfma_f32_32x32x16_bf16(pa, vf1, oacc1, 0, 0, 0);
    }
    __builtin_amdgcn_s_setprio(0);

    u16* tk = K0; K0 = K1; K1 = K2; K2 = tk;
    u16* tv = V0; V0 = V1; V1 = V2; V2 = tv;
  }

  // partial epilogue: NO division; write o (f32), l, m
  const size_t pbase = ((size_t)(kh * 24 + head)) * Sc;
#pragma unroll
  for (int rr = 0; rr < 16; ++rr) {
    int qi = (rr & 3) + 8 * (rr >> 2) + 4 * hi2;
    int q = q0 + w * 32 + qi;
    float* dst = Po + (pbase + q) * HDc;
    dst[l31]      = oacc0[rr];
    dst[32 + l31] = oacc1[rr];
  }
  if (l31 == 0) {                                 // lanes 0 and 32
#pragma unroll
    for (int rr = 0; rr < 16; ++rr) {
      int qi = (rr & 3) + 8 * (rr >> 2) + 4 * hi2;
      Pl[pbase + q0 + w * 32 + qi] = lacc[rr];
    }
  }
  if (hi2 == 0) Pm[pbase + q0 + w * 32 + l31] = mrow;
}

// ---------------- combine: merge the two kv-halves exactly ----------------

__global__ void combine(const float* __restrict__ Po, const float* __restrict__ Pl,
                        const float* __restrict__ Pm, u16* __restrict__ ctxg) {
  int idx = blockIdx.x * 256 + threadIdx.x;       // 24*2048*16
  int head = idx >> 15;
  int rem = idx & 32767;
  int q = rem >> 4, d4 = rem & 15;
  size_t hq = (size_t)head * Sc + q;
  const size_t HSTR = (size_t)24 * Sc;            // kh stride for l/m
  float m0 = Pm[hq], m1 = Pm[HSTR + hq];
  float l0 = Pl[hq], l1 = Pl[HSTR + hq];
  float M = fmaxf(m0, m1);
  float e0 = exp2f(m0 - M), e1 = exp2f(m1 - M);
  float inv = 1.0f / (l0 * e0 + l1 * e1);
  const float4* P4 = reinterpret_cast<const float4*>(Po);
  float4 o0 = P4[hq * 16 + d4];
  float4 o1 = P4[(HSTR + hq) * 16 + d4];
  u16x4 pk;
  pk[0] = f2bf((o0.x * e0 + o1.x * e1) * inv);
  pk[1] = f2bf((o0.y * e0 + o1.y * e1) * inv);
  pk[2] = f2bf((o0.z * e0 + o1.z * e1) * inv);
  pk[3] = f2bf((o0.w * e0 + o1.w * e1) * inv);
  int b = head / NHc, h = head - b * NHc;
  *reinterpret_cast<u16x4*>(ctxg + (size_t)(b * Sc + q) * Hc + h * HDc + d4 * 4) = pk;
}

// ---------------- launch ----------------

extern "C" void kernel_launch(void* const* d_in, const int* in_sizes, int n_in,
                              void* d_out, int out_size, void* d_ws, size_t ws_size,
                              hipStream_t stream) {
  const float* hs  = (const float*)d_in[0];
  const int* mask  = (const int*)d_in[1];
  const float* Wq  = (const float*)d_in[2];
  const float* bq  = (const float*)d_in[3];
  const float* Wk  = (const float*)d_in[4];
  const float* bk  = (const float*)d_in[5];
  const float* Wv  = (const float*)d_in[6];
  const float* bv  = (const float*)d_in[7];
  const float* Wo  = (const float*)d_in[8];
  const float* bo  = (const float*)d_in[9];

  char* ws = (char*)d_ws;
  u16* Xb  = (u16*)(ws);                      // 4096x768 bf16
  u16* Wtq = (u16*)(ws + 6291456);            // 4x 768x768 bf16
  u16* Wtk = Wtq + 589824;
  u16* Wtv = Wtk + 589824;
  u16* Wto = Wtv + 589824;
  u16* Qb  = (u16*)(ws + 11010048);           // [24][2048][64]
  u16* Kb  = Qb + 3145728;                    // [24][2048][64]
  u16* Vtb = Kb + 3145728;                    // [24][64][2048] (kv-permuted)
  u16* Ctx = Vtb + 3145728;                   // 4096x768 bf16
  u16* Mns = Ctx + 3145728;                   // [2][2048] maskones (perm)
  // split-path partials (past byte 36,184,064)
  float* Po = (float*)(ws + 36184064);        // [2][24][2048][64] f32, 25.2MB
  float* Pl = (float*)(ws + 61349888);        // [2][24][2048] f32
  float* Pm = (float*)(ws + 61743104);        // [2][24][2048] f32 -> end 62,136,320
  const bool use_split = ws_size >= 62136320ull;

  cvt_bf16<<<(Mc * Hc / 4 + 255) / 256, 256, 0, stream>>>(hs, Xb, Mc * Hc / 4, mask, Mns);
  wtrans<<<dim3(24, 24, 4), dim3(32, 8), 0, stream>>>(Wq, Wk, Wv, Wo, Wtq, Wtk, Wtv, Wto);
  qkv_gemm<<<dim3(32, 6, 3), 256, 0, stream>>>(Xb, Wtq, Wtk, Wtv, bq, bk, bv, mask, Qb, Kb, Vtb);
  if (use_split) {
    attn_split<<<1536, 128, 0, stream>>>(Qb, Kb, Vtb, Mns, Po, Pl, Pm);
    combine<<<3072, 256, 0, stream>>>(Po, Pl, Pm, Ctx);
  } else {
    attn_full<<<768, 128, 0, stream>>>(Qb, Kb, Vtb, Mns, Ctx);
  }
  out_gemm<<<dim3(32, 6), 256, 0, stream>>>(Ctx, Wto, bo, (float*)d_out);
}

// Round 11
// 142.496 us; speedup vs baseline: 1.1198x; 1.1164x over previous
//
#include <hip/hip_runtime.h>
#include <hip/hip_bf16.h>

#define DI __device__ __forceinline__

using bf16x8 = __attribute__((ext_vector_type(8))) short;
using f32x4  = __attribute__((ext_vector_type(4))) float;
using f32x16 = __attribute__((ext_vector_type(16))) float;
using u16    = unsigned short;
using u16x4  = __attribute__((ext_vector_type(4))) unsigned short;

constexpr int Bc = 2, Sc = 2048, Hc = 768, NHc = 12, HDc = 64;
constexpr int Mc = Bc * Sc;                 // 4096 rows
constexpr float L2E = 1.4426950408889634f;

DI u16 f2bf(float f) {
  union { float f; unsigned u; } c; c.f = f;
  unsigned u = c.u;
  return (u16)((u + 0x7fffu + ((u >> 16) & 1u)) >> 16);   // RNE
}

DI unsigned f2bf2(float a, float b) {
  float2 t; t.x = a; t.y = b;
  __hip_bfloat162 h = __float22bfloat162_rn(t);
  union { __hip_bfloat162 h; unsigned u; } c; c.h = h;
  return c.u;
}

// hardware packed cvt (T12-verified recipe: lo -> D[15:0], hi -> D[31:16])
DI unsigned cvtpk(float lo, float hi) {
  unsigned r;
  asm("v_cvt_pk_bf16_f32 %0, %1, %2" : "=v"(r) : "v"(lo), "v"(hi));
  return r;
}

// raw v_exp_f32: exactly 2^x, no ocml fixup
DI float exp2a(float x) {
  float r;
  asm("v_exp_f32 %0, %1" : "=v"(r) : "v"(x));
  return r;
}

DI void gload_lds16(const void* g, void* l) {
  __builtin_amdgcn_global_load_lds(
      (__attribute__((address_space(1))) void*)(g),
      (__attribute__((address_space(3))) void*)(l), 16, 0, 0);
}

// ---------------- prep kernels ----------------

// also converts mask -> maskones bf16, PERMUTED within 16-groups (swap kv
// bits 2<->3) so attn's PV B-frag slots are one contiguous 16B chunk.
__global__ void cvt_bf16(const float* __restrict__ x, u16* __restrict__ y, int n4,
                         const int* __restrict__ maskg, u16* __restrict__ mones) {
  int i = blockIdx.x * 256 + threadIdx.x;
  if (i >= n4) return;
  float4 v = reinterpret_cast<const float4*>(x)[i];
  u16x4 o;
  o[0] = f2bf(v.x); o[1] = f2bf(v.y); o[2] = f2bf(v.z); o[3] = f2bf(v.w);
  reinterpret_cast<u16x4*>(y)[i] = o;
  if (i < Bc * Sc / 4) {
    int j = i & 3;
    int js = ((j & 1) << 1) | ((j >> 1) & 1);      // swap bits within quad
    int isrc = (i & ~3) | js;
    int4 mv = reinterpret_cast<const int4*>(maskg)[isrc];
    u16x4 m;
    m[0] = f2bf((float)mv.x); m[1] = f2bf((float)mv.y);
    m[2] = f2bf((float)mv.z); m[3] = f2bf((float)mv.w);
    reinterpret_cast<u16x4*>(mones)[i] = m;
  }
}

// Wt[n][k] = W[k][n], bf16
__global__ void wtrans(const float* __restrict__ Wq, const float* __restrict__ Wk,
                       const float* __restrict__ Wv, const float* __restrict__ Wo,
                       u16* __restrict__ Tq, u16* __restrict__ Tk,
                       u16* __restrict__ Tv, u16* __restrict__ To) {
  __shared__ float tile[32][33];
  const float* W; u16* T;
  switch (blockIdx.z) {
    case 0:  W = Wq; T = Tq; break;
    case 1:  W = Wk; T = Tk; break;
    case 2:  W = Wv; T = Tv; break;
    default: W = Wo; T = To; break;
  }
  int tx = threadIdx.x, ty = threadIdx.y;
  int n0 = blockIdx.x * 32, k0 = blockIdx.y * 32;
#pragma unroll
  for (int j = 0; j < 4; ++j) tile[ty + j * 8][tx] = W[(k0 + ty + j * 8) * Hc + n0 + tx];
  __syncthreads();
#pragma unroll
  for (int j = 0; j < 4; ++j) T[(n0 + ty + j * 8) * Hc + k0 + tx] = f2bf(tile[tx][ty + j * 8]);
}

// ---------------- GEMM core (C[m][n] = sum_k A[m][k]*Bt[n][k]) ----------------

DI void gemm_core(const u16* __restrict__ Ag, const u16* __restrict__ Btg,
                  u16* Asm, u16* Bsm, int m0, int n0,
                  int tid, int lane, int wr, int wc, f32x4 acc[4][4]) {
  const int lo = lane & 15, hi = lane >> 4;
  const int r1 = tid >> 2, c1 = tid & 3;
  for (int kt = 0; kt < Hc / 32; ++kt) {
    const int k0 = kt * 32;
    {
      int row = r1, cg = c1 ^ ((row >> 1) & 3);
      gload_lds16(Ag  + (size_t)(row + m0) * Hc + k0 + cg * 8, Asm + tid * 8);
      gload_lds16(Btg + (size_t)(row + n0) * Hc + k0 + cg * 8, Bsm + tid * 8);
      row = r1 + 64; cg = c1 ^ ((row >> 1) & 3);
      gload_lds16(Ag  + (size_t)(row + m0) * Hc + k0 + cg * 8, Asm + (tid + 256) * 8);
      gload_lds16(Btg + (size_t)(row + n0) * Hc + k0 + cg * 8, Bsm + (tid + 256) * 8);
    }
    __syncthreads();
    bf16x8 af[4], bf[4];
#pragma unroll
    for (int m = 0; m < 4; ++m) {
      int rowa = wr * 64 + m * 16 + lo;
      af[m] = *reinterpret_cast<const bf16x8*>(Asm + rowa * 32 + ((hi ^ ((rowa >> 1) & 3)) * 8));
      int rowb = wc * 64 + m * 16 + lo;
      bf[m] = *reinterpret_cast<const bf16x8*>(Bsm + rowb * 32 + ((hi ^ ((rowb >> 1) & 3)) * 8));
    }
#pragma unroll
    for (int m = 0; m < 4; ++m)
#pragma unroll
      for (int n = 0; n < 4; ++n)
        acc[m][n] = __builtin_amdgcn_mfma_f32_16x16x32_bf16(af[m], bf[n], acc[m][n], 0, 0, 0);
    __syncthreads();
  }
}

// ---------------- QKV projection ----------------

__launch_bounds__(256)
__global__ void qkv_gemm(const u16* __restrict__ Xb,
                         const u16* __restrict__ Wtq, const u16* __restrict__ Wtk,
                         const u16* __restrict__ Wtv,
                         const float* __restrict__ bq, const float* __restrict__ bk,
                         const float* __restrict__ bv, const int* __restrict__ maskg,
                         u16* __restrict__ Qo, u16* __restrict__ Ko, u16* __restrict__ Vto) {
  __shared__ __attribute__((aligned(16))) u16 Asm[128 * 32];
  __shared__ __attribute__((aligned(16))) u16 Bsm[128 * 32];
  const int tid = threadIdx.x, lane = tid & 63, w = tid >> 6;
  const int wr = w >> 1, wc = w & 1;
  const int m0 = blockIdx.x * 128, n0 = blockIdx.y * 128;
  const int z = blockIdx.z;
  const u16* Bt = (z == 0) ? Wtq : ((z == 1) ? Wtk : Wtv);
  const float* bias = (z == 0) ? bq : ((z == 1) ? bk : bv);
  f32x4 acc[4][4] = {};
  gemm_core(Xb, Bt, Asm, Bsm, m0, n0, tid, lane, wr, wc, acc);
  const int lo = lane & 15, hi = lane >> 4;
  const float scl = (z == 0) ? 0.125f * L2E : 1.0f;    // fold log2(e) into Q
#pragma unroll
  for (int m = 0; m < 4; ++m)
#pragma unroll
    for (int n = 0; n < 4; ++n)
#pragma unroll
      for (int r = 0; r < 4; ++r) {
        int gm = m0 + wr * 64 + m * 16 + hi * 4 + r;
        int gn = n0 + wc * 64 + n * 16 + lo;
        float v = (acc[m][n][r] + bias[gn]) * scl;
        int b = gm >> 11, s = gm & 2047, h = gn >> 6, d = gn & 63;
        if (z == 2) {
          v *= (float)maskg[b * Sc + s];       // zero masked value rows
          int sp = (s & ~12) | ((s & 4) << 1) | ((s & 8) >> 1);   // kv-permute
          Vto[((b * NHc + h) * HDc + d) * Sc + sp] = f2bf(v);
        } else {
          int idx = (((b * NHc + h) * Sc) + s) * HDc + d;
          if (z == 0) Qo[idx] = f2bf(v); else Ko[idx] = f2bf(v);
        }
      }
}

// ---------------- output projection ----------------

__launch_bounds__(256)
__global__ void out_gemm(const u16* __restrict__ Ctx, const u16* __restrict__ Wto,
                         const float* __restrict__ bo, float* __restrict__ out) {
  __shared__ __attribute__((aligned(16))) u16 Asm[128 * 32];
  __shared__ __attribute__((aligned(16))) u16 Bsm[128 * 32];
  const int tid = threadIdx.x, lane = tid & 63, w = tid >> 6;
  const int wr = w >> 1, wc = w & 1;
  const int m0 = blockIdx.x * 128, n0 = blockIdx.y * 128;
  f32x4 acc[4][4] = {};
  gemm_core(Ctx, Wto, Asm, Bsm, m0, n0, tid, lane, wr, wc, acc);
  const int lo = lane & 15, hi = lane >> 4;
#pragma unroll
  for (int m = 0; m < 4; ++m)
#pragma unroll
    for (int n = 0; n < 4; ++n)
#pragma unroll
      for (int r = 0; r < 4; ++r) {
        int gm = m0 + wr * 64 + m * 16 + hi * 4 + r;
        int gn = n0 + wc * 64 + n * 16 + lo;
        out[(size_t)gm * Hc + gn] = acc[m][n][r] + bo[gn];
      }
}

// ---------------- attention helpers ----------------

DI bf16x8 lds_rd(const u16* base, int row, int c8) {       // 8 chunks/row
  return *reinterpret_cast<const bf16x8*>(base + row * 64 + ((c8 ^ (row & 7)) << 3));
}
DI bf16x8 lds_rd4(const u16* base, int row, int c4) {      // 4 chunks/row
  return *reinterpret_cast<const bf16x8*>(base + row * 32 + ((c4 ^ (row & 3)) << 3));
}

DI float vmax16(const f32x16& v) {
  float a0 = fmaxf(v[0], v[8]),  a1 = fmaxf(v[1], v[9]);
  float a2 = fmaxf(v[2], v[10]), a3 = fmaxf(v[3], v[11]);
  float a4 = fmaxf(v[4], v[12]), a5 = fmaxf(v[5], v[13]);
  float a6 = fmaxf(v[6], v[14]), a7 = fmaxf(v[7], v[15]);
  float b0 = fmaxf(a0, a4), b1 = fmaxf(a1, a5);
  float b2 = fmaxf(a2, a6), b3 = fmaxf(a3, a7);
  return fmaxf(fmaxf(b0, b1), fmaxf(b2, b3));
}

// lane-local pack of 8 consecutive C/D regs into one A-frag (hw cvt_pk)
DI bf16x8 pkfrag0(const f32x16& p) {
  union { unsigned u[4]; bf16x8 v; } a;
  a.u[0] = cvtpk(p[0], p[1]); a.u[1] = cvtpk(p[2], p[3]);
  a.u[2] = cvtpk(p[4], p[5]); a.u[3] = cvtpk(p[6], p[7]);
  return a.v;
}
DI bf16x8 pkfrag1(const f32x16& p) {
  union { unsigned u[4]; bf16x8 v; } a;
  a.u[0] = cvtpk(p[8], p[9]);   a.u[1] = cvtpk(p[10], p[11]);
  a.u[2] = cvtpk(p[12], p[13]); a.u[3] = cvtpk(p[14], p[15]);
  return a.v;
}

// software-RNE variants for the (unused unless ws is small) fallback kernel
DI bf16x8 pkfrag0s(const f32x16& p) {
  union { unsigned u[4]; bf16x8 v; } a;
  a.u[0] = f2bf2(p[0], p[1]); a.u[1] = f2bf2(p[2], p[3]);
  a.u[2] = f2bf2(p[4], p[5]); a.u[3] = f2bf2(p[6], p[7]);
  return a.v;
}
DI bf16x8 pkfrag1s(const f32x16& p) {
  union { unsigned u[4]; bf16x8 v; } a;
  a.u[0] = f2bf2(p[8], p[9]);   a.u[1] = f2bf2(p[10], p[11]);
  a.u[2] = f2bf2(p[12], p[13]); a.u[3] = f2bf2(p[14], p[15]);
  return a.v;
}

#define ATTN_BAR()  do { __builtin_amdgcn_sched_barrier(0); \
                         __builtin_amdgcn_s_barrier();      \
                         __builtin_amdgcn_sched_barrier(0); } while (0)

// ---------------- attn_full: r7-proven kernel (fallback path) ----------------

__launch_bounds__(128)
__global__ void attn_full(const u16* __restrict__ Qg, const u16* __restrict__ Kg,
                          const u16* __restrict__ Vtg, const u16* __restrict__ monesG,
                          u16* __restrict__ ctxg) {
  __shared__ __attribute__((aligned(16))) u16 Ksm[3][64 * 64];
  __shared__ __attribute__((aligned(16))) u16 Vsm[3][64 * 64];
  __shared__ __attribute__((aligned(16))) u16 Mo[Sc];

  const int tid = threadIdx.x, lane = tid & 63, w = tid >> 6;
  const int l31 = lane & 31, hi2 = lane >> 5;
  const int id = blockIdx.x;
  const int xcd = id & 7, sub = id >> 3;
  const int head = xcd * 3 + (sub >> 5);
  const int q0 = (sub & 31) * 64;
  const int b = head / NHc, h = head % NHc;
  const u16* Qh = Qg + (size_t)head * Sc * HDc;
  const u16* Kh = Kg + (size_t)head * Sc * HDc;
  const u16* Vh = Vtg + (size_t)head * HDc * Sc;

#pragma unroll
  for (int j = 0; j < 2; ++j) {
    int ch = tid + j * 128;
    gload_lds16(monesG + (size_t)b * Sc + ch * 8, Mo + ch * 8);
  }
  const int qglob = q0 + w * 32 + l31;
  bf16x8 qf[4];
#pragma unroll
  for (int c = 0; c < 4; ++c)
    qf[c] = *reinterpret_cast<const bf16x8*>(Qh + (size_t)qglob * HDc + c * 16 + hi2 * 8);
  __syncthreads();

  u16 *K0 = &Ksm[0][0], *K1 = &Ksm[1][0], *K2 = &Ksm[2][0];
  u16 *V0 = &Vsm[0][0], *V1 = &Vsm[1][0], *V2 = &Vsm[2][0];
  auto stage = [&](u16* Kd, u16* Vd, int kv0) {
#pragma unroll
    for (int j = 0; j < 4; ++j) {
      int ch = tid + j * 128;
      int row = ch >> 3, cg = (ch & 7) ^ (row & 7);
      gload_lds16(Kh + (size_t)(kv0 + row) * HDc + cg * 8, Kd + ch * 8);
    }
#pragma unroll
    for (int j = 0; j < 4; ++j) {
      int ch = tid + j * 128;
      int row = ch >> 3, cg = (ch & 7) ^ (row & 7);
      gload_lds16(Vh + (size_t)row * Sc + kv0 + cg * 8, Vd + ch * 8);
    }
  };
  stage(K0, V0, 0);
  stage(K1, V1, 64);

  f32x16 oacc0 = {}, oacc1 = {}, lacc = {};
  float mrow = -1e30f;
  constexpr int NT = Sc / 64;
  for (int t = 0; t < NT; ++t) {
    ATTN_BAR();
    if (t + 2 < NT) {
      stage(K2, V2, (t + 2) * 64);
      asm volatile("s_waitcnt vmcnt(16)" ::: "memory");
    } else if (t + 2 == NT) {
      asm volatile("s_waitcnt vmcnt(8)" ::: "memory");
    } else {
      asm volatile("s_waitcnt vmcnt(0)" ::: "memory");
    }
    ATTN_BAR();
    const u16* Ks = K0;
    const u16* Vs = V0;
    f32x16 s0 = {}, s1 = {};
    __builtin_amdgcn_s_setprio(1);
#pragma unroll
    for (int c = 0; c < 4; ++c) {
      bf16x8 kf0 = lds_rd(Ks, l31, 2 * c + hi2);
      bf16x8 kf1 = lds_rd(Ks, 32 + l31, 2 * c + hi2);
      s0 = __builtin_amdgcn_mfma_f32_32x32x16_bf16(kf0, qf[c], s0, 0, 0, 0);
      s1 = __builtin_amdgcn_mfma_f32_32x32x16_bf16(kf1, qf[c], s1, 0, 0, 0);
    }
    __builtin_amdgcn_s_setprio(0);
    float pmax = fmaxf(vmax16(s0), vmax16(s1));
    pmax = fmaxf(pmax, __shfl_xor(pmax, 32, 64));
    if (!__all(pmax - mrow <= 8.0f)) {
      float nm = fmaxf(mrow, pmax);
      float sc = exp2f(mrow - nm);
      mrow = nm;
#pragma unroll
      for (int rr = 0; rr < 16; ++rr) {
        int qi = (rr & 3) + 8 * (rr >> 2) + 4 * hi2;
        float sb = __shfl(sc, qi, 64);
        oacc0[rr] *= sb; oacc1[rr] *= sb; lacc[rr] *= sb;
      }
    }
#pragma unroll
    for (int j = 0; j < 16; ++j) s0[j] = exp2f(s0[j] - mrow);
#pragma unroll
    for (int j = 0; j < 16; ++j) s1[j] = exp2f(s1[j] - mrow);
    bf16x8 paf[4];
    paf[0] = pkfrag0s(s0); paf[1] = pkfrag1s(s0);
    paf[2] = pkfrag0s(s1); paf[3] = pkfrag1s(s1);
    __builtin_amdgcn_s_setprio(1);
#pragma unroll
    for (int c4 = 0; c4 < 4; ++c4) {
      bf16x8 mo = *reinterpret_cast<const bf16x8*>(Mo + t * 64 + c4 * 16 + hi2 * 8);
      bf16x8 vf0 = lds_rd(Vs, l31, 2 * c4 + hi2);
      bf16x8 vf1 = lds_rd(Vs, 32 + l31, 2 * c4 + hi2);
      lacc  = __builtin_amdgcn_mfma_f32_32x32x16_bf16(paf[c4], mo, lacc, 0, 0, 0);
      oacc0 = __builtin_amdgcn_mfma_f32_32x32x16_bf16(paf[c4], vf0, oacc0, 0, 0, 0);
      oacc1 = __builtin_amdgcn_mfma_f32_32x32x16_bf16(paf[c4], vf1, oacc1, 0, 0, 0);
    }
    __builtin_amdgcn_s_setprio(0);
    u16* tk = K0; K0 = K1; K1 = K2; K2 = tk;
    u16* tv = V0; V0 = V1; V1 = V2; V2 = tv;
  }
#pragma unroll
  for (int rr = 0; rr < 16; ++rr) {
    float inv = 1.0f / lacc[rr];
    int qi = (rr & 3) + 8 * (rr >> 2) + 4 * hi2;
    int s = q0 + w * 32 + qi;
    size_t base = (size_t)(b * Sc + s) * Hc + h * HDc;
    ctxg[base + l31]      = f2bf(oacc0[rr] * inv);
    ctxg[base + 32 + l31] = f2bf(oacc1[rr] * inv);
  }
}

// ---------------- attn_split: kv-split x2, KVBLK=32, QUAD buffer ------------
// 1536 blocks. 34KB LDS -> 4 blocks/CU. ONE barrier per tile: with 4 buffers,
// stage(t+2) overwrites the buffer read at t-2, whose ds_reads completed
// before BAR(t-1) (each read feeds an MFMA issued pre-barrier), and the
// writer runs after BAR(t-1). vmcnt(8) before the barrier publishes tile t.

__launch_bounds__(128)
__global__ void attn_split(const u16* __restrict__ Qg, const u16* __restrict__ Kg,
                           const u16* __restrict__ Vtg, const u16* __restrict__ monesG,
                           float* __restrict__ Po, float* __restrict__ Pl,
                           float* __restrict__ Pm) {
  __shared__ __attribute__((aligned(16))) u16 Ksm[4][32 * 64];
  __shared__ __attribute__((aligned(16))) u16 Vsm[4][64 * 32];
  __shared__ __attribute__((aligned(16))) u16 Mo[1024];

  const int tid = threadIdx.x, lane = tid & 63, w = tid >> 6;
  const int l31 = lane & 31, hi2 = lane >> 5;
  const int id = blockIdx.x;
  const int xcd = id & 7, sub = id >> 3;          // sub 0..191
  const int head = xcd * 3 + (sub >> 6);          // 3 heads/XCD
  const int r = sub & 63;
  const int q0 = (r >> 1) * 64;
  const int kh = r & 1;
  const int b = head / NHc;
  const int kvbase = kh * 1024;

  const u16* Qh = Qg + (size_t)head * Sc * HDc;
  const u16* Kh = Kg + (size_t)head * Sc * HDc;
  const u16* Vh = Vtg + (size_t)head * HDc * Sc;

  // maskones half (pre-permuted)
  gload_lds16(monesG + (size_t)b * Sc + kvbase + tid * 8, Mo + tid * 8);

  const int qglob = q0 + w * 32 + l31;
  bf16x8 qf[4];
#pragma unroll
  for (int c = 0; c < 4; ++c)
    qf[c] = *reinterpret_cast<const bf16x8*>(Qh + (size_t)qglob * HDc + c * 16 + hi2 * 8);
  __syncthreads();                                // drain Q + Mo vmem

  u16 *K0 = &Ksm[0][0], *K1 = &Ksm[1][0], *K2 = &Ksm[2][0], *K3 = &Ksm[3][0];
  u16 *V0 = &Vsm[0][0], *V1 = &Vsm[1][0], *V2 = &Vsm[2][0], *V3 = &Vsm[3][0];

  // per-thread staging: 2 K chunks + 2 V chunks (4 vmem ops/thread)
  auto stage = [&](u16* Kd, u16* Vd, int kv0) {
#pragma unroll
    for (int j = 0; j < 2; ++j) {
      int ch = tid + j * 128;                     // 0..255
      int row = ch >> 3, cg = (ch & 7) ^ (row & 7);   // 32 rows x 8 chunks
      gload_lds16(Kh + (size_t)(kv0 + row) * HDc + cg * 8, Kd + ch * 8);
    }
#pragma unroll
    for (int j = 0; j < 2; ++j) {
      int ch = tid + j * 128;
      int row = ch >> 2, cg = (ch & 3) ^ (row & 3);   // 64 rows x 4 chunks
      gload_lds16(Vh + (size_t)row * Sc + kv0 + cg * 8, Vd + ch * 8);
    }
  };
  stage(K0, V0, kvbase);
  stage(K1, V1, kvbase + 32);

  f32x16 oacc0 = {}, oacc1 = {}, lacc = {};
  float mrow = -1e30f;
  constexpr int NT = 32;                          // 1024 kv / 32
  for (int t = 0; t < NT; ++t) {
    if (t + 2 < NT) {
      stage(K2, V2, kvbase + (t + 2) * 32);
      asm volatile("s_waitcnt vmcnt(8)" ::: "memory");    // tile t resident
    } else if (t + 2 == NT) {
      asm volatile("s_waitcnt vmcnt(4)" ::: "memory");
    } else {
      asm volatile("s_waitcnt vmcnt(0)" ::: "memory");
    }
    ATTN_BAR();                                   // publish tile t to all waves
    const u16* Ks = K0;
    const u16* Vs = V0;

    // QK^T swapped: 32 kv rows; lane owns q = l31
    f32x16 s0 = {};
    __builtin_amdgcn_s_setprio(1);
#pragma unroll
    for (int c = 0; c < 4; ++c) {
      bf16x8 kf = lds_rd(Ks, l31, 2 * c + hi2);
      s0 = __builtin_amdgcn_mfma_f32_32x32x16_bf16(kf, qf[c], s0, 0, 0, 0);
    }
    __builtin_amdgcn_s_setprio(0);

    float pmax = vmax16(s0);
    pmax = fmaxf(pmax, __shfl_xor(pmax, 32, 64));
    if (!__all(pmax - mrow <= 8.0f)) {
      float nm = fmaxf(mrow, pmax);
      float sc = exp2a(mrow - nm);
      mrow = nm;
#pragma unroll
      for (int rr = 0; rr < 16; ++rr) {
        int qi = (rr & 3) + 8 * (rr >> 2) + 4 * hi2;
        float sb = __shfl(sc, qi, 64);
        oacc0[rr] *= sb; oacc1[rr] *= sb; lacc[rr] *= sb;
      }
    }
#pragma unroll
    for (int j = 0; j < 16; ++j) s0[j] = exp2a(s0[j] - mrow);

    bf16x8 paf0 = pkfrag0(s0), paf1 = pkfrag1(s0);

    __builtin_amdgcn_s_setprio(1);
#pragma unroll
    for (int c4 = 0; c4 < 2; ++c4) {
      bf16x8 pa = c4 ? paf1 : paf0;
      bf16x8 mo = *reinterpret_cast<const bf16x8*>(Mo + t * 32 + c4 * 16 + hi2 * 8);
      bf16x8 vf0 = lds_rd4(Vs, l31, 2 * c4 + hi2);
      bf16x8 vf1 = lds_rd4(Vs, 32 + l31, 2 * c4 + hi2);
      lacc  = __builtin_amdgcn_mfma_f32_32x32x16_bf16(pa, mo, lacc, 0, 0, 0);
      oacc0 = __builtin_amdgcn_mfma_f32_32x32x16_bf16(pa, vf0, oacc0, 0, 0, 0);
      oacc1 = __builtin_amdgcn_mfma_f32_32x32x16_bf16(pa, vf1, oacc1, 0, 0, 0);
    }
    __builtin_amdgcn_s_setprio(0);

    // rotate 4 buffers: K0<-K1<-K2<-K3<-K0
    u16* tk = K0; K0 = K1; K1 = K2; K2 = K3; K3 = tk;
    u16* tv = V0; V0 = V1; V1 = V2; V2 = V3; V3 = tv;
  }

  // partial epilogue: NO division; write o (f32), l, m
  const size_t pbase = ((size_t)(kh * 24 + head)) * Sc;
#pragma unroll
  for (int rr = 0; rr < 16; ++rr) {
    int qi = (rr & 3) + 8 * (rr >> 2) + 4 * hi2;
    int q = q0 + w * 32 + qi;
    float* dst = Po + (pbase + q) * HDc;
    dst[l31]      = oacc0[rr];
    dst[32 + l31] = oacc1[rr];
  }
  if (l31 == 0) {                                 // lanes 0 and 32
#pragma unroll
    for (int rr = 0; rr < 16; ++rr) {
      int qi = (rr & 3) + 8 * (rr >> 2) + 4 * hi2;
      Pl[pbase + q0 + w * 32 + qi] = lacc[rr];
    }
  }
  if (hi2 == 0) Pm[pbase + q0 + w * 32 + l31] = mrow;
}

// ---------------- combine: merge the two kv-halves exactly ----------------

__global__ void combine(const float* __restrict__ Po, const float* __restrict__ Pl,
                        const float* __restrict__ Pm, u16* __restrict__ ctxg) {
  int idx = blockIdx.x * 256 + threadIdx.x;       // 24*2048*16
  int head = idx >> 15;
  int rem = idx & 32767;
  int q = rem >> 4, d4 = rem & 15;
  size_t hq = (size_t)head * Sc + q;
  const size_t HSTR = (size_t)24 * Sc;            // kh stride for l/m
  float m0 = Pm[hq], m1 = Pm[HSTR + hq];
  float l0 = Pl[hq], l1 = Pl[HSTR + hq];
  float M = fmaxf(m0, m1);
  float e0 = exp2f(m0 - M), e1 = exp2f(m1 - M);
  float inv = 1.0f / (l0 * e0 + l1 * e1);
  const float4* P4 = reinterpret_cast<const float4*>(Po);
  float4 o0 = P4[hq * 16 + d4];
  float4 o1 = P4[(HSTR + hq) * 16 + d4];
  u16x4 pk;
  pk[0] = f2bf((o0.x * e0 + o1.x * e1) * inv);
  pk[1] = f2bf((o0.y * e0 + o1.y * e1) * inv);
  pk[2] = f2bf((o0.z * e0 + o1.z * e1) * inv);
  pk[3] = f2bf((o0.w * e0 + o1.w * e1) * inv);
  int b = head / NHc, h = head - b * NHc;
  *reinterpret_cast<u16x4*>(ctxg + (size_t)(b * Sc + q) * Hc + h * HDc + d4 * 4) = pk;
}

// ---------------- launch ----------------

extern "C" void kernel_launch(void* const* d_in, const int* in_sizes, int n_in,
                              void* d_out, int out_size, void* d_ws, size_t ws_size,
                              hipStream_t stream) {
  const float* hs  = (const float*)d_in[0];
  const int* mask  = (const int*)d_in[1];
  const float* Wq  = (const float*)d_in[2];
  const float* bq  = (const float*)d_in[3];
  const float* Wk  = (const float*)d_in[4];
  const float* bk  = (const float*)d_in[5];
  const float* Wv  = (const float*)d_in[6];
  const float* bv  = (const float*)d_in[7];
  const float* Wo  = (const float*)d_in[8];
  const float* bo  = (const float*)d_in[9];

  char* ws = (char*)d_ws;
  u16* Xb  = (u16*)(ws);                      // 4096x768 bf16
  u16* Wtq = (u16*)(ws + 6291456);            // 4x 768x768 bf16
  u16* Wtk = Wtq + 589824;
  u16* Wtv = Wtk + 589824;
  u16* Wto = Wtv + 589824;
  u16* Qb  = (u16*)(ws + 11010048);           // [24][2048][64]
  u16* Kb  = Qb + 3145728;                    // [24][2048][64]
  u16* Vtb = Kb + 3145728;                    // [24][64][2048] (kv-permuted)
  u16* Ctx = Vtb + 3145728;                   // 4096x768 bf16
  u16* Mns = Ctx + 3145728;                   // [2][2048] maskones (perm)
  // split-path partials (past byte 36,184,064)
  float* Po = (float*)(ws + 36184064);        // [2][24][2048][64] f32, 25.2MB
  float* Pl = (float*)(ws + 61349888);        // [2][24][2048] f32
  float* Pm = (float*)(ws + 61743104);        // [2][24][2048] f32 -> end 62,136,320
  const bool use_split = ws_size >= 62136320ull;

  cvt_bf16<<<(Mc * Hc / 4 + 255) / 256, 256, 0, stream>>>(hs, Xb, Mc * Hc / 4, mask, Mns);
  wtrans<<<dim3(24, 24, 4), dim3(32, 8), 0, stream>>>(Wq, Wk, Wv, Wo, Wtq, Wtk, Wtv, Wto);
  qkv_gemm<<<dim3(32, 6, 3), 256, 0, stream>>>(Xb, Wtq, Wtk, Wtv, bq, bk, bv, mask, Qb, Kb, Vtb);
  if (use_split) {
    attn_split<<<1536, 128, 0, stream>>>(Qb, Kb, Vtb, Mns, Po, Pl, Pm);
    combine<<<3072, 256, 0, stream>>>(Po, Pl, Pm, Ctx);
  } else {
    attn_full<<<768, 128, 0, stream>>>(Qb, Kb, Vtb, Mns, Ctx);
  }
  out_gemm<<<dim3(32, 6), 256, 0, stream>>>(Ctx, Wto, bo, (float*)d_out);
}